// Round 7
// baseline (5516.530 us; speedup 1.0000x reference)
//
#include <hip/hip_runtime.h>

#define DD 256
#define KK 8192
#define HW 1024
#define NROWS 16384
#define NELEM 4194304
#define MT 32
#define MARGIN 6e-4f

typedef __attribute__((ext_vector_type(8))) short short8;
typedef __attribute__((ext_vector_type(4))) float f32x4;
typedef unsigned short ushort;
typedef unsigned int uint;

// ---- exact replication of numpy pairwise_sum (n=256) over squares ----
__device__ __forceinline__ float np_pw128_sq(const float* p) {
  float r[8];
#pragma unroll
  for (int j = 0; j < 8; ++j) r[j] = __fmul_rn(p[j], p[j]);
  for (int i = 8; i < 128; i += 8) {
#pragma unroll
    for (int j = 0; j < 8; ++j)
      r[j] = __fadd_rn(r[j], __fmul_rn(p[i + j], p[i + j]));
  }
  return __fadd_rn(__fadd_rn(__fadd_rn(r[0], r[1]), __fadd_rn(r[2], r[3])),
                   __fadd_rn(__fadd_rn(r[4], r[5]), __fadd_rn(r[6], r[7])));
}

__device__ __forceinline__ ushort f2bf(float x) {   // RNE float->bf16 bits
  uint u = __float_as_uint(x);
  u += 0x7FFF + ((u >> 16) & 1);
  return (ushort)(u >> 16);
}

// ---------------- ||e_k||^2, numpy-exact ----------------
__global__ __launch_bounds__(256) void vq_norms(const float* __restrict__ cb,
                                                float* __restrict__ Bk) {
  int k = blockIdx.x * 256 + threadIdx.x;
  const float* p = cb + (size_t)k * DD;
  Bk[k] = __fadd_rn(np_pw128_sq(p), np_pw128_sq(p + 128));
}

// ---------------- ||z_n||^2, numpy-exact ----------------
__global__ __launch_bounds__(256) void vq_arow(const float* __restrict__ z,
                                               float* __restrict__ Arow) {
  int n = blockIdx.x * 256 + threadIdx.x;
  int bimg = n >> 10, hw = n & 1023;
  const float* zp = z + (size_t)bimg * DD * HW + hw;
  float h[2];
#pragma unroll
  for (int half = 0; half < 2; ++half) {
    float r[8];
#pragma unroll
    for (int j = 0; j < 8; ++j) {
      float v = zp[(size_t)(half * 128 + j) * HW];
      r[j] = __fmul_rn(v, v);
    }
    for (int i = 8; i < 128; i += 8) {
#pragma unroll
      for (int j = 0; j < 8; ++j) {
        float v = zp[(size_t)(half * 128 + i + j) * HW];
        r[j] = __fadd_rn(r[j], __fmul_rn(v, v));
      }
    }
    h[half] = __fadd_rn(__fadd_rn(__fadd_rn(r[0], r[1]), __fadd_rn(r[2], r[3])),
                        __fadd_rn(__fadd_rn(r[4], r[5]), __fadd_rn(r[6], r[7])));
  }
  Arow[n] = __fadd_rn(h[0], h[1]);
}

// ---- build z A-fragments: zA[((r0*8+s)*64+lane)*8+j] = bf16(z[row=r0*16+(lane&15)][d=s*32+(lane>>4)*8+j]) ----
__global__ __launch_bounds__(256) void vq_zA(const float* __restrict__ z,
                                             ushort* __restrict__ zA) {
  int tid = blockIdx.x * 256 + threadIdx.x;      // 524288 threads
  int r0 = tid >> 9, s = (tid >> 6) & 7, lane = tid & 63;
  int n = r0 * 16 + (lane & 15);
  int bimg = n >> 10, hw = n & 1023;
  int dbase = s * 32 + (lane >> 4) * 8;
  const float* zp = z + ((size_t)bimg * DD + dbase) * HW + hw;
  ushort b[8];
#pragma unroll
  for (int j = 0; j < 8; ++j) b[j] = f2bf(zp[(size_t)j * HW]);
  uint4 pk;
  pk.x = b[0] | ((uint)b[1] << 16);
  pk.y = b[2] | ((uint)b[3] << 16);
  pk.z = b[4] | ((uint)b[5] << 16);
  pk.w = b[6] | ((uint)b[7] << 16);
  *(uint4*)(zA + (size_t)tid * 8) = pk;
}

// ---- build codebook B-fragments: cbB[((g*8+s)*64+lane)*8+j] = bf16(cb[code=g*16+(lane&15)][d=s*32+(lane>>4)*8+j]) ----
__global__ __launch_bounds__(256) void vq_cbB(const float* __restrict__ cb,
                                              ushort* __restrict__ cbB) {
  int tid = blockIdx.x * 256 + threadIdx.x;      // 262144 threads
  int g = tid >> 9, s = (tid >> 6) & 7, lane = tid & 63;
  int code = g * 16 + (lane & 15);
  int dbase = s * 32 + (lane >> 4) * 8;
  const float* p = cb + (size_t)code * DD + dbase;
  ushort b[8];
#pragma unroll
  for (int j = 0; j < 8; ++j) b[j] = f2bf(p[j]);
  uint4 pk;
  pk.x = b[0] | ((uint)b[1] << 16);
  pk.y = b[2] | ((uint)b[3] << 16);
  pk.z = b[4] | ((uint)b[5] << 16);
  pk.w = b[6] | ((uint)b[7] << 16);
  *(uint4*)(cbB + (size_t)tid * 8) = pk;
}

// -------- MFMA screen + exact re-rank of flagged 64-code groups --------
// grid 1024: block b -> rows (b>>1)*32..+32, codes [(b&1)*4096, +4096)
// NOTE r4/r5 lesson: min-waves/EU stays 2; higher values cap VGPRs and
// spill the accumulators to scratch (WRITE_SIZE blows up to GBs).
__global__ __launch_bounds__(256, 2) void vq_screen(
    const ushort* __restrict__ zA, const ushort* __restrict__ cbB,
    const float* __restrict__ z, const float* __restrict__ cb,
    const float* __restrict__ Bk, const float* __restrict__ Arow,
    unsigned long long* __restrict__ rowBest) {
  __shared__ float zt[MT][DD + 1];   // fp32 z rows for exact phase (32.9 KB)
  __shared__ float gmin[MT][65];     // screen min per (row, 64-code group)
  __shared__ float thr[MT];

  const int t = threadIdx.x;
  const int rowTile = blockIdx.x >> 1;
  const int khalf = blockIdx.x & 1;
  const int n0 = rowTile * MT;
  const int bimg = n0 >> 10, hw0 = n0 & 1023;
  const float* zb = z + (size_t)bimg * DD * HW + hw0;

  for (int li = t; li < MT * DD; li += 256) {
    int d = li >> 5, r = li & 31;
    zt[r][d] = zb[d * HW + r];
  }
  __syncthreads();

  const int w = t >> 6, lane = t & 63;
  const int rowg = w >> 1;        // 0/1: rows rowg*16..+15
  const int codeseg = w & 1;      // 0/1: 2048-code segment within half
  const int r0 = rowTile * 2 + rowg;
  const int quad = lane >> 4;

  short8 aF[8];
#pragma unroll
  for (int s = 0; s < 8; ++s)
    aF[s] = *(const short8*)(zA + ((size_t)(r0 * 8 + s) * 64 + lane) * 8);

  const int gg0 = (khalf * 4096 + codeseg * 2048) >> 4;   // first 16-code group
  float m4[4] = {3.4e38f, 3.4e38f, 3.4e38f, 3.4e38f};

  for (int g16 = 0; g16 < 128; ++g16) {
    const int gg = gg0 + g16;
    f32x4 acc = {0.f, 0.f, 0.f, 0.f};
    const ushort* bp = cbB + ((size_t)gg * 8 * 64 + lane) * 8;
#pragma unroll
    for (int s = 0; s < 8; ++s) {
      short8 bF = *(const short8*)(bp + (size_t)s * 64 * 8);
      acc = __builtin_amdgcn_mfma_f32_16x16x32_bf16(aF[s], bF, acc, 0, 0, 0);
    }
    const float Bs = Bk[(gg << 4) + (lane & 15)];
#pragma unroll
    for (int reg = 0; reg < 4; ++reg)
      m4[reg] = fminf(m4[reg], fmaf(-2.f, acc[reg], Bs));   // screen value
    if ((g16 & 3) == 3) {      // every 64 codes: reduce over 16 lanes, store
#pragma unroll
      for (int off = 1; off < 16; off <<= 1)
#pragma unroll
        for (int reg = 0; reg < 4; ++reg)
          m4[reg] = fminf(m4[reg], __shfl_xor(m4[reg], off));
      if ((lane & 15) == 0) {
        int col = codeseg * 32 + (g16 >> 2);
#pragma unroll
        for (int reg = 0; reg < 4; ++reg)
          gmin[rowg * 16 + quad * 4 + reg][col] = m4[reg];
      }
#pragma unroll
      for (int reg = 0; reg < 4; ++reg) m4[reg] = 3.4e38f;
    }
  }
  __syncthreads();

  if (t < MT) {
    float mn = gmin[t][0];
    for (int c = 1; c < 64; ++c) mn = fminf(mn, gmin[t][c]);
    thr[t] = mn + MARGIN;
  }
  __syncthreads();

  // exact phase: thread t handles row t>>3, group slots (t&7)+8i
  const int row = t >> 3;
  const float Ar = Arow[n0 + row];
  for (int gi = t & 7; gi < 64; gi += 8) {
    if (gmin[row][gi] <= thr[row]) {
      const int kbase = khalf * 4096 + gi * 64;
      float bd = 3.4e38f;
      int bi = 0;
      for (int c = 0; c < 64; ++c) {        // ascending k, strict <
        const int code = kbase + c;
        const float* ep = cb + (size_t)code * DD;
        float dot = 0.f;
        for (int d = 0; d < DD; ++d) dot = fmaf(zt[row][d], ep[d], dot);
        float dist = __fsub_rn(__fadd_rn(Ar, Bk[code]), __fmul_rn(2.f, dot));
        if (dist < bd) { bd = dist; bi = code; }
      }
      unsigned long long key =
          ((unsigned long long)__float_as_uint(bd) << 32) | (unsigned)bi;
      atomicMin(&rowBest[n0 + row], key);   // lexicographic (dist, idx) min
    }
  }
}

// -------- epilogue: idx/hist + z_q_st + loss --------
__global__ __launch_bounds__(256) void vq_out(
    const float* __restrict__ z, const float* __restrict__ cb,
    const unsigned long long* __restrict__ rowBest, float* __restrict__ out,
    int* __restrict__ hist, float* __restrict__ loss_acc) {
  __shared__ int kwin[MT];
  __shared__ float lred[4];
  const int t = threadIdx.x;
  const int n0 = blockIdx.x * MT;
  const int bimg = n0 >> 10, hw0 = n0 & 1023;

  if (t < MT) {
    int n = n0 + t;
    int bi = (int)(rowBest[n] & 0xFFFFFFFFull);
    kwin[t] = bi;
    atomicAdd(&hist[bi], 1);
    out[(size_t)NELEM + 1 + n] = (float)bi;
  }
  __syncthreads();

  const float* zb = z + (size_t)bimg * DD * HW + hw0;
  float lsum = 0.f;
  for (int it = 0; it < MT * DD / 256; ++it) {
    int li = it * 256 + t;
    int d = li >> 5, r = li & 31;
    float ze = zb[d * HW + r];
    float zq = cb[(size_t)kwin[r] * DD + d];
    float diff = __fsub_rn(zq, ze);
    float st = __fadd_rn(ze, diff);        // z_e + (z_q - z_e)
    out[(size_t)(bimg * DD + d) * HW + hw0 + r] = st;
    lsum = fmaf(diff, diff, lsum);
  }
#pragma unroll
  for (int off = 32; off > 0; off >>= 1) lsum += __shfl_down(lsum, off);
  if ((t & 63) == 0) lred[t >> 6] = lsum;
  __syncthreads();
  if (t == 0)
    atomicAdd(loss_acc, ((lred[0] + lred[1]) + (lred[2] + lred[3])));
}

// ---------------- finalize: vq_loss + perplexity ----------------
__global__ __launch_bounds__(256) void vq_final(const int* __restrict__ hist,
                                                const float* __restrict__ loss,
                                                float* __restrict__ out) {
  __shared__ float sred[256];
  int t = threadIdx.x;
  float s = 0.f;
  for (int k = t; k < KK; k += 256) {
    float p = (float)hist[k] * (1.f / 16384.f);
    s += p * logf(p + 1e-10f);
  }
  sred[t] = s;
  __syncthreads();
  for (int off = 128; off > 0; off >>= 1) {
    if (t < off) sred[t] += sred[t + off];
    __syncthreads();
  }
  if (t == 0) {
    float L = loss[0] / (float)NELEM;
    out[NELEM] = 1.25f * L;
    out[(size_t)NELEM + 1 + NROWS] = expf(-sred[0]);
  }
}

extern "C" void kernel_launch(void* const* d_in, const int* in_sizes, int n_in,
                              void* d_out, int out_size, void* d_ws, size_t ws_size,
                              hipStream_t stream) {
  const float* z = (const float*)d_in[0];   // (16,256,32,32) fp32
  const float* cb = (const float*)d_in[1];  // (8192,256) fp32
  float* out = (float*)d_out;               // fp32: [z_q_st | loss | idx | perp]

  float* wsf = (float*)d_ws;
  int* hist = (int*)d_ws;                                   // 8192 ints
  float* loss = wsf + 8192;                                 // 1
  float* Bk = wsf + 8448;                                   // 8192
  float* Arow = wsf + 16640;                                // 16384
  unsigned long long* rowBest = (unsigned long long*)(wsf + 33024);  // 16384 u64
  ushort* zA = (ushort*)(wsf + 65792);                      // 4.19M ushorts
  ushort* cbB = (ushort*)(wsf + 65792 + 2097152);           // 2.10M ushorts

  hipMemsetAsync(d_ws, 0, 8448 * sizeof(float), stream);
  hipMemsetAsync(rowBest, 0xFF, NROWS * sizeof(unsigned long long), stream);
  vq_norms<<<KK / 256, 256, 0, stream>>>(cb, Bk);
  vq_arow<<<NROWS / 256, 256, 0, stream>>>(z, Arow);
  vq_zA<<<2048, 256, 0, stream>>>(z, zA);
  vq_cbB<<<1024, 256, 0, stream>>>(cb, cbB);
  vq_screen<<<(NROWS / MT) * 2, 256, 0, stream>>>(zA, cbB, z, cb, Bk, Arow, rowBest);
  vq_out<<<NROWS / MT, 256, 0, stream>>>(z, cb, rowBest, out, hist, loss);
  vq_final<<<1, 256, 0, stream>>>(hist, loss, out);
}

// Round 8
// 624.379 us; speedup vs baseline: 8.8352x; 8.8352x over previous
//
#include <hip/hip_runtime.h>

#define DD 256
#define KK 8192
#define HW 1024
#define NROWS 16384
#define NELEM 4194304
#define MT 32
#define MARGIN 6e-4f
#define WCAP 512

typedef __attribute__((ext_vector_type(8))) short short8;
typedef __attribute__((ext_vector_type(4))) float f32x4;
typedef unsigned short ushort;
typedef unsigned int uint;
typedef unsigned long long u64;

// ---- exact replication of numpy pairwise_sum (n=256) over squares ----
__device__ __forceinline__ float np_pw128_sq(const float* p) {
  float r[8];
#pragma unroll
  for (int j = 0; j < 8; ++j) r[j] = __fmul_rn(p[j], p[j]);
  for (int i = 8; i < 128; i += 8) {
#pragma unroll
    for (int j = 0; j < 8; ++j)
      r[j] = __fadd_rn(r[j], __fmul_rn(p[i + j], p[i + j]));
  }
  return __fadd_rn(__fadd_rn(__fadd_rn(r[0], r[1]), __fadd_rn(r[2], r[3])),
                   __fadd_rn(__fadd_rn(r[4], r[5]), __fadd_rn(r[6], r[7])));
}

__device__ __forceinline__ ushort f2bf(float x) {   // RNE float->bf16 bits
  uint u = __float_as_uint(x);
  u += 0x7FFF + ((u >> 16) & 1);
  return (ushort)(u >> 16);
}

// ---------------- ||e_k||^2, numpy-exact ----------------
__global__ __launch_bounds__(256) void vq_norms(const float* __restrict__ cb,
                                                float* __restrict__ Bk) {
  int k = blockIdx.x * 256 + threadIdx.x;
  const float* p = cb + (size_t)k * DD;
  Bk[k] = __fadd_rn(np_pw128_sq(p), np_pw128_sq(p + 128));
}

// ---------------- ||z_n||^2, numpy-exact ----------------
__global__ __launch_bounds__(256) void vq_arow(const float* __restrict__ z,
                                               float* __restrict__ Arow) {
  int n = blockIdx.x * 256 + threadIdx.x;
  int bimg = n >> 10, hw = n & 1023;
  const float* zp = z + (size_t)bimg * DD * HW + hw;
  float h[2];
#pragma unroll
  for (int half = 0; half < 2; ++half) {
    float r[8];
#pragma unroll
    for (int j = 0; j < 8; ++j) {
      float v = zp[(size_t)(half * 128 + j) * HW];
      r[j] = __fmul_rn(v, v);
    }
    for (int i = 8; i < 128; i += 8) {
#pragma unroll
      for (int j = 0; j < 8; ++j) {
        float v = zp[(size_t)(half * 128 + i + j) * HW];
        r[j] = __fadd_rn(r[j], __fmul_rn(v, v));
      }
    }
    h[half] = __fadd_rn(__fadd_rn(__fadd_rn(r[0], r[1]), __fadd_rn(r[2], r[3])),
                        __fadd_rn(__fadd_rn(r[4], r[5]), __fadd_rn(r[6], r[7])));
  }
  Arow[n] = __fadd_rn(h[0], h[1]);
}

// ---------------- cbT[d][k] = cb[k][d] ----------------
__global__ __launch_bounds__(256) void vq_transpose(const float* __restrict__ cb,
                                                    float* __restrict__ cbT) {
  __shared__ float tile[64][65];
  int k0 = blockIdx.x * 64, d0 = blockIdx.y * 64;
  for (int li = threadIdx.x; li < 64 * 64; li += 256) {
    int kk = li >> 6, dd = li & 63;
    tile[kk][dd] = cb[(size_t)(k0 + kk) * DD + d0 + dd];
  }
  __syncthreads();
  for (int li = threadIdx.x; li < 64 * 64; li += 256) {
    int dd = li >> 6, kk = li & 63;
    cbT[(size_t)(d0 + dd) * KK + k0 + kk] = tile[kk][dd];
  }
}

// ---- codebook B-fragments (layout verified in round 7):
// cbB[((g*8+s)*64+lane)*8+j] = bf16(cb[code=g*16+(lane&15)][d=s*32+(lane>>4)*8+j])
__global__ __launch_bounds__(256) void vq_cbB(const float* __restrict__ cb,
                                              ushort* __restrict__ cbB) {
  int tid = blockIdx.x * 256 + threadIdx.x;      // 262144 threads
  int g = tid >> 9, s = (tid >> 6) & 7, lane = tid & 63;
  int code = g * 16 + (lane & 15);
  int dbase = s * 32 + (lane >> 4) * 8;
  const float* p = cb + (size_t)code * DD + dbase;
  ushort b[8];
#pragma unroll
  for (int j = 0; j < 8; ++j) b[j] = f2bf(p[j]);
  uint4 pk;
  pk.x = b[0] | ((uint)b[1] << 16);
  pk.y = b[2] | ((uint)b[3] << 16);
  pk.z = b[4] | ((uint)b[5] << 16);
  pk.w = b[6] | ((uint)b[7] << 16);
  *(uint4*)(cbB + (size_t)tid * 8) = pk;
}

// ======== fused: screen (MFMA) + exact re-rank (wave/group) + epilogue ========
// grid 512: block = 32 rows, all 8192 codes. Plain launch_bounds (r4/r5 lesson:
// min-waves>=4 caps VGPRs and spills accumulators).
__global__ __launch_bounds__(256) void vq_fused(
    const float* __restrict__ z, const float* __restrict__ cbT,
    const float* __restrict__ cb, const ushort* __restrict__ cbB,
    const float* __restrict__ Bk, const float* __restrict__ Arow,
    float* __restrict__ out, int* __restrict__ hist,
    float* __restrict__ loss_acc, u64* __restrict__ rowBest) {
  __shared__ float zt[MT][DD + 1];    // 32.9 KB fp32 z rows (kept to the end)
  __shared__ float gmin[MT][128];     // 16.4 KB screen min per 64-code group
  __shared__ float thr[MT];
  __shared__ float ArS[MT];
  __shared__ int wl[WCAP];
  __shared__ int wcnt;
  __shared__ int kwin[MT];
  __shared__ float lred[4];

  const int t = threadIdx.x;
  const int n0 = blockIdx.x * MT;
  const int bimg = n0 >> 10, hw0 = n0 & 1023;
  const float* zb = z + (size_t)bimg * DD * HW + hw0;

  if (t == 0) wcnt = 0;
  if (t < MT) ArS[t] = Arow[n0 + t];
  for (int li = t; li < MT * DD; li += 256) {
    int d = li >> 5, r = li & 31;
    zt[r][d] = zb[d * HW + r];
  }
  __syncthreads();

  const int w = t >> 6, lane = t & 63;
  const int rowg = w & 1;       // 16-row group
  const int codeseg = w >> 1;   // 4096-code segment
  const int quad = lane >> 4, n16 = lane & 15;

  // A-fragments from zt: A[m=lane&15][k=quad*8+j], m89-verified layout
  short8 aF[8];
#pragma unroll
  for (int s = 0; s < 8; ++s) {
    const float* zp = &zt[rowg * 16 + n16][s * 32 + quad * 8];
    short8 v;
#pragma unroll
    for (int j = 0; j < 8; ++j) v[j] = (short)f2bf(zp[j]);
    aF[s] = v;
  }

  // ---- MFMA screen over my 4096 codes (256 groups of 16) ----
  const int gbase = codeseg * 256;
  float m4[4] = {3.4e38f, 3.4e38f, 3.4e38f, 3.4e38f};
#pragma unroll 2
  for (int gl = 0; gl < 256; ++gl) {
    const int gg = gbase + gl;
    f32x4 acc = {0.f, 0.f, 0.f, 0.f};
    const ushort* bp = cbB + ((size_t)gg * 8 * 64 + lane) * 8;
#pragma unroll
    for (int s = 0; s < 8; ++s) {
      short8 bF = *(const short8*)(bp + (size_t)s * 512);
      acc = __builtin_amdgcn_mfma_f32_16x16x32_bf16(aF[s], bF, acc, 0, 0, 0);
    }
    const float Bs = Bk[(gg << 4) + n16];
#pragma unroll
    for (int reg = 0; reg < 4; ++reg)
      m4[reg] = fminf(m4[reg], fmaf(-2.f, acc[reg], Bs));
    if ((gl & 3) == 3) {   // 64 codes done: reduce over the 16 code-lanes
#pragma unroll
      for (int off = 1; off < 16; off <<= 1)
#pragma unroll
        for (int reg = 0; reg < 4; ++reg)
          m4[reg] = fminf(m4[reg], __shfl_xor(m4[reg], off));
      if (n16 == 0) {
        int col = codeseg * 64 + (gl >> 2);
#pragma unroll
        for (int reg = 0; reg < 4; ++reg)
          gmin[rowg * 16 + quad * 4 + reg][col] = m4[reg];
      }
#pragma unroll
      for (int reg = 0; reg < 4; ++reg) m4[reg] = 3.4e38f;
    }
  }
  __syncthreads();

  // ---- per-row global threshold, build worklist ----
  if (t < MT) {
    float mn = gmin[t][0];
    for (int c = 1; c < 128; ++c) mn = fminf(mn, gmin[t][c]);
    thr[t] = mn + MARGIN;
  }
  __syncthreads();
  for (int idx = t; idx < MT * 128; idx += 256) {
    int r = idx >> 7, g = idx & 127;
    if (gmin[r][g] <= thr[r]) {
      int pos = atomicAdd(&wcnt, 1);
      if (pos < WCAP) {
        wl[pos] = (r << 16) | g;
      } else {   // overflow fallback (never in practice): scalar exact scan
        float bd = 3.4e38f;
        int bi = 0;
        for (int c = 0; c < 64; ++c) {
          int code = g * 64 + c;
          const float* ep = cb + (size_t)code * DD;
          float dot = 0.f;
          for (int d = 0; d < DD; ++d) dot = fmaf(zt[r][d], ep[d], dot);
          float dist = __fsub_rn(__fadd_rn(ArS[r], Bk[code]),
                                 __fmul_rn(2.f, dot));
          if (dist < bd) { bd = dist; bi = code; }
        }
        atomicMin(&rowBest[n0 + r],
                  ((u64)__float_as_uint(bd) << 32) | (unsigned)bi);
      }
    }
  }
  __syncthreads();

  // ---- exact re-rank: one wave per flagged (row, 64-code group) ----
  // lane = code within group; dot = ascending-d fmaf chain (numpy-exact
  // pipeline order, identical to rounds 2-6); coalesced cbT loads.
  const int cnt = min(wcnt, WCAP);
  for (int e = w; e < cnt; e += 4) {
    const int ent = wl[e];
    const int r = ent >> 16, g = ent & 0xFFFF;
    const int code = g * 64 + lane;
    const float* cp = cbT + code;
    float dot = 0.f;
    for (int d = 0; d < DD; ++d)
      dot = fmaf(zt[r][d], cp[(size_t)d * KK], dot);
    float bd = __fsub_rn(__fadd_rn(ArS[r], Bk[code]), __fmul_rn(2.f, dot));
    int bi = code;
#pragma unroll
    for (int off = 1; off < 64; off <<= 1) {   // lex (dist, idx) min
      float pd = __shfl_xor(bd, off);
      int pi = __shfl_xor(bi, off);
      if (pd < bd || (pd == bd && pi < bi)) { bd = pd; bi = pi; }
    }
    if (lane == 0)
      atomicMin(&rowBest[n0 + r],
                ((u64)__float_as_uint(bd) << 32) | (unsigned)bi);
  }
  __syncthreads();

  // ---- epilogue: indices + hist + z_q_st + loss (zt still resident) ----
  if (t < MT) {
    u64 key = atomicMin(&rowBest[n0 + t], 0xFFFFFFFFFFFFFFFFull);  // read
    int bi = (int)(key & 0xFFFFFFFFull);
    kwin[t] = bi;
    atomicAdd(&hist[bi], 1);
    out[(size_t)NELEM + 1 + n0 + t] = (float)bi;
  }
  __syncthreads();

  float lsum = 0.f;
  for (int it = 0; it < MT * DD / 256; ++it) {
    int li = it * 256 + t;
    int d = li >> 5, r = li & 31;
    float ze = zt[r][d];
    float zq = cb[(size_t)kwin[r] * DD + d];
    float diff = __fsub_rn(zq, ze);
    float st = __fadd_rn(ze, diff);        // z_e + (z_q - z_e)
    out[(size_t)(bimg * DD + d) * HW + hw0 + r] = st;
    lsum = fmaf(diff, diff, lsum);
  }
#pragma unroll
  for (int off = 32; off > 0; off >>= 1) lsum += __shfl_down(lsum, off);
  if (lane == 0) lred[w] = lsum;
  __syncthreads();
  if (t == 0)
    atomicAdd(loss_acc, ((lred[0] + lred[1]) + (lred[2] + lred[3])));
}

// ---------------- finalize: vq_loss + perplexity ----------------
__global__ __launch_bounds__(256) void vq_final(const int* __restrict__ hist,
                                                const float* __restrict__ loss,
                                                float* __restrict__ out) {
  __shared__ float sred[256];
  int t = threadIdx.x;
  float s = 0.f;
  for (int k = t; k < KK; k += 256) {
    float p = (float)hist[k] * (1.f / 16384.f);
    s += p * logf(p + 1e-10f);
  }
  sred[t] = s;
  __syncthreads();
  for (int off = 128; off > 0; off >>= 1) {
    if (t < off) sred[t] += sred[t + off];
    __syncthreads();
  }
  if (t == 0) {
    float L = loss[0] / (float)NELEM;
    out[NELEM] = 1.25f * L;
    out[(size_t)NELEM + 1 + NROWS] = expf(-sred[0]);
  }
}

extern "C" void kernel_launch(void* const* d_in, const int* in_sizes, int n_in,
                              void* d_out, int out_size, void* d_ws, size_t ws_size,
                              hipStream_t stream) {
  const float* z = (const float*)d_in[0];   // (16,256,32,32) fp32
  const float* cb = (const float*)d_in[1];  // (8192,256) fp32
  float* out = (float*)d_out;               // fp32: [z_q_st | loss | idx | perp]

  float* wsf = (float*)d_ws;
  int* hist = (int*)d_ws;                          // 8192 ints
  float* loss = wsf + 8192;                        // 1 (+pad)
  float* Bk = wsf + 8448;                          // 8192
  float* Arow = wsf + 16640;                       // 16384
  u64* rowBest = (u64*)(wsf + 33024);              // 16384 u64 (128 KB)
  ushort* cbB = (ushort*)(wsf + 65792);            // 2.10M ushorts (4.2 MB)
  float* cbT = wsf + 65792 + 1048576;              // 2M floats (8 MB)

  hipMemsetAsync(d_ws, 0, 8448 * sizeof(float), stream);
  hipMemsetAsync(rowBest, 0xFF, NROWS * sizeof(u64), stream);
  vq_transpose<<<dim3(KK / 64, DD / 64), 256, 0, stream>>>(cb, cbT);
  vq_norms<<<KK / 256, 256, 0, stream>>>(cb, Bk);
  vq_arow<<<NROWS / 256, 256, 0, stream>>>(z, Arow);
  vq_cbB<<<1024, 256, 0, stream>>>(cb, cbB);
  vq_fused<<<NROWS / MT, 256, 0, stream>>>(z, cbT, cb, cbB, Bk, Arow, out,
                                           hist, loss, rowBest);
  vq_final<<<1, 256, 0, stream>>>(hist, loss, out);
}

// Round 9
// 568.248 us; speedup vs baseline: 9.7080x; 1.0988x over previous
//
#include <hip/hip_runtime.h>

#define DD 256
#define KK 8192
#define HW 1024
#define NROWS 16384
#define NELEM 4194304
#define MT 32
#define MARGIN 6e-4f
#define WCAP 512

typedef __attribute__((ext_vector_type(8))) short short8;
typedef __attribute__((ext_vector_type(4))) float f32x4;
typedef unsigned short ushort;
typedef unsigned int uint;
typedef unsigned long long u64;

// ---- exact replication of numpy pairwise_sum (n=256) over squares ----
__device__ __forceinline__ float np_pw128_sq(const float* p) {
  float r[8];
#pragma unroll
  for (int j = 0; j < 8; ++j) r[j] = __fmul_rn(p[j], p[j]);
  for (int i = 8; i < 128; i += 8) {
#pragma unroll
    for (int j = 0; j < 8; ++j)
      r[j] = __fadd_rn(r[j], __fmul_rn(p[i + j], p[i + j]));
  }
  return __fadd_rn(__fadd_rn(__fadd_rn(r[0], r[1]), __fadd_rn(r[2], r[3])),
                   __fadd_rn(__fadd_rn(r[4], r[5]), __fadd_rn(r[6], r[7])));
}

__device__ __forceinline__ ushort f2bf(float x) {   // RNE float->bf16 bits
  uint u = __float_as_uint(x);
  u += 0x7FFF + ((u >> 16) & 1);
  return (ushort)(u >> 16);
}

// ---------------- ||e_k||^2, numpy-exact ----------------
__global__ __launch_bounds__(256) void vq_norms(const float* __restrict__ cb,
                                                float* __restrict__ Bk) {
  int k = blockIdx.x * 256 + threadIdx.x;
  const float* p = cb + (size_t)k * DD;
  Bk[k] = __fadd_rn(np_pw128_sq(p), np_pw128_sq(p + 128));
}

// ---------------- ||z_n||^2, numpy-exact ----------------
__global__ __launch_bounds__(256) void vq_arow(const float* __restrict__ z,
                                               float* __restrict__ Arow) {
  int n = blockIdx.x * 256 + threadIdx.x;
  int bimg = n >> 10, hw = n & 1023;
  const float* zp = z + (size_t)bimg * DD * HW + hw;
  float h[2];
#pragma unroll
  for (int half = 0; half < 2; ++half) {
    float r[8];
#pragma unroll
    for (int j = 0; j < 8; ++j) {
      float v = zp[(size_t)(half * 128 + j) * HW];
      r[j] = __fmul_rn(v, v);
    }
    for (int i = 8; i < 128; i += 8) {
#pragma unroll
      for (int j = 0; j < 8; ++j) {
        float v = zp[(size_t)(half * 128 + i + j) * HW];
        r[j] = __fadd_rn(r[j], __fmul_rn(v, v));
      }
    }
    h[half] = __fadd_rn(__fadd_rn(__fadd_rn(r[0], r[1]), __fadd_rn(r[2], r[3])),
                        __fadd_rn(__fadd_rn(r[4], r[5]), __fadd_rn(r[6], r[7])));
  }
  Arow[n] = __fadd_rn(h[0], h[1]);
}

// ---------------- cbT[d][k] = cb[k][d] ----------------
__global__ __launch_bounds__(256) void vq_transpose(const float* __restrict__ cb,
                                                    float* __restrict__ cbT) {
  __shared__ float tile[64][65];
  int k0 = blockIdx.x * 64, d0 = blockIdx.y * 64;
  for (int li = threadIdx.x; li < 64 * 64; li += 256) {
    int kk = li >> 6, dd = li & 63;
    tile[kk][dd] = cb[(size_t)(k0 + kk) * DD + d0 + dd];
  }
  __syncthreads();
  for (int li = threadIdx.x; li < 64 * 64; li += 256) {
    int dd = li >> 6, kk = li & 63;
    cbT[(size_t)(d0 + dd) * KK + k0 + kk] = tile[kk][dd];
  }
}

// ---- codebook B-fragments (layout verified in rounds 7/8):
// cbB[((g*8+s)*64+lane)*8+j] = bf16(cb[code=g*16+(lane&15)][d=s*32+(lane>>4)*8+j])
__global__ __launch_bounds__(256) void vq_cbB(const float* __restrict__ cb,
                                              ushort* __restrict__ cbB) {
  int tid = blockIdx.x * 256 + threadIdx.x;      // 262144 threads
  int g = tid >> 9, s = (tid >> 6) & 7, lane = tid & 63;
  int code = g * 16 + (lane & 15);
  int dbase = s * 32 + (lane >> 4) * 8;
  const float* p = cb + (size_t)code * DD + dbase;
  ushort b[8];
#pragma unroll
  for (int j = 0; j < 8; ++j) b[j] = f2bf(p[j]);
  uint4 pk;
  pk.x = b[0] | ((uint)b[1] << 16);
  pk.y = b[2] | ((uint)b[3] << 16);
  pk.z = b[4] | ((uint)b[5] << 16);
  pk.w = b[6] | ((uint)b[7] << 16);
  *(uint4*)(cbB + (size_t)tid * 8) = pk;
}

// ======== fused: screen (MFMA) + exact re-rank (wave/group) + epilogue ========
// Plain launch_bounds (r4/r5 lesson: min-waves>=4 caps VGPRs -> spill).
__global__ __launch_bounds__(256) void vq_fused(
    const float* __restrict__ z, const float* __restrict__ cbT,
    const float* __restrict__ cb, const ushort* __restrict__ cbB,
    const float* __restrict__ Bk, const float* __restrict__ Arow,
    float* __restrict__ out, int* __restrict__ hist,
    float* __restrict__ loss_acc, u64* __restrict__ rowBest) {
  __shared__ float zt[MT][DD + 1];    // 32.9 KB fp32 z rows (kept to the end)
  __shared__ float gmin[MT][128];     // 16.4 KB screen min per 64-code group
  __shared__ float thr[MT];
  __shared__ float ArS[MT];
  __shared__ int wl[WCAP];
  __shared__ int wcnt;
  __shared__ int kwin[MT];
  __shared__ float lred[4];

  const int t = threadIdx.x;
  const int n0 = blockIdx.x * MT;
  const int bimg = n0 >> 10, hw0 = n0 & 1023;
  const float* zb = z + (size_t)bimg * DD * HW + hw0;

  if (t == 0) wcnt = 0;
  if (t < MT) ArS[t] = Arow[n0 + t];
  for (int li = t; li < MT * DD; li += 256) {
    int d = li >> 5, r = li & 31;
    zt[r][d] = zb[d * HW + r];
  }
  __syncthreads();

  const int w = t >> 6, lane = t & 63;
  const int rowg = w & 1;       // 16-row group
  const int codeseg = w >> 1;   // 4096-code segment
  const int quad = lane >> 4, n16 = lane & 15;

  // A-fragments from zt: A[m=lane&15][k=quad*8+j] (m89-verified layout)
  short8 aF[8];
#pragma unroll
  for (int s = 0; s < 8; ++s) {
    const float* zp = &zt[rowg * 16 + n16][s * 32 + quad * 8];
    short8 v;
#pragma unroll
    for (int j = 0; j < 8; ++j) v[j] = (short)f2bf(zp[j]);
    aF[s] = v;
  }

  // ---- MFMA screen over my 4096 codes (256 groups of 16) ----
  const int gbase = codeseg * 256;
  float m4[4] = {3.4e38f, 3.4e38f, 3.4e38f, 3.4e38f};
#pragma unroll 2
  for (int gl = 0; gl < 256; ++gl) {
    const int gg = gbase + gl;
    f32x4 acc = {0.f, 0.f, 0.f, 0.f};
    const ushort* bp = cbB + ((size_t)gg * 8 * 64 + lane) * 8;
#pragma unroll
    for (int s = 0; s < 8; ++s) {
      short8 bF = *(const short8*)(bp + (size_t)s * 512);
      acc = __builtin_amdgcn_mfma_f32_16x16x32_bf16(aF[s], bF, acc, 0, 0, 0);
    }
    const float Bs = Bk[(gg << 4) + n16];
#pragma unroll
    for (int reg = 0; reg < 4; ++reg)
      m4[reg] = fminf(m4[reg], fmaf(-2.f, acc[reg], Bs));
    if ((gl & 3) == 3) {   // 64 codes done: reduce over the 16 code-lanes
#pragma unroll
      for (int off = 1; off < 16; off <<= 1)
#pragma unroll
        for (int reg = 0; reg < 4; ++reg)
          m4[reg] = fminf(m4[reg], __shfl_xor(m4[reg], off));
      if (n16 == 0) {
        int col = codeseg * 64 + (gl >> 2);
#pragma unroll
        for (int reg = 0; reg < 4; ++reg)
          gmin[rowg * 16 + quad * 4 + reg][col] = m4[reg];
      }
#pragma unroll
      for (int reg = 0; reg < 4; ++reg) m4[reg] = 3.4e38f;
    }
  }
  __syncthreads();

  // ---- per-row global threshold, build worklist ----
  if (t < MT) {
    float mn = gmin[t][0];
    for (int c = 1; c < 128; ++c) mn = fminf(mn, gmin[t][c]);
    thr[t] = mn + MARGIN;
  }
  __syncthreads();
  for (int idx = t; idx < MT * 128; idx += 256) {
    int r = idx >> 7, g = idx & 127;
    if (gmin[r][g] <= thr[r]) {
      int pos = atomicAdd(&wcnt, 1);
      if (pos < WCAP) {
        wl[pos] = (r << 16) | g;
      } else {   // overflow fallback (never in practice): scalar exact scan
        float bd = 3.4e38f;
        int bi = 0;
        for (int c = 0; c < 64; ++c) {
          int code = g * 64 + c;
          const float* ep = cb + (size_t)code * DD;
          float dot = 0.f;
          for (int d = 0; d < DD; ++d) dot = fmaf(zt[r][d], ep[d], dot);
          float dist = __fsub_rn(__fadd_rn(ArS[r], Bk[code]),
                                 __fmul_rn(2.f, dot));
          if (dist < bd) { bd = dist; bi = code; }
        }
        atomicMin(&rowBest[n0 + r],
                  ((u64)__float_as_uint(bd) << 32) | (unsigned)bi);
      }
    }
  }
  __syncthreads();

  // ---- exact re-rank: one wave per flagged (row, 64-code group) ----
  // lane = code. KEY FIX (r8 post-mortem): batch the 64 strided cbT loads
  // into registers FIRST (independent, all in flight), THEN run the
  // ascending-d fmaf chain (numpy-exact order unchanged). The r8 version
  // fused load+fma -> one ~250-cyc dependent stall per d-step (~500 us).
  const int cnt = min(wcnt, WCAP);
  for (int e = w; e < cnt; e += 4) {
    const int ent = wl[e];
    const int r = ent >> 16, g = ent & 0xFFFF;
    const int code = g * 64 + lane;
    const float* cp = cbT + code;
    float dot = 0.f;
#pragma unroll
    for (int d0 = 0; d0 < DD; d0 += 64) {
      float v[64];
#pragma unroll
      for (int j = 0; j < 64; ++j) v[j] = cp[(size_t)(d0 + j) * KK];
#pragma unroll
      for (int j = 0; j < 64; ++j) dot = fmaf(zt[r][d0 + j], v[j], dot);
    }
    float bd = __fsub_rn(__fadd_rn(ArS[r], Bk[code]), __fmul_rn(2.f, dot));
    int bi = code;
#pragma unroll
    for (int off = 1; off < 64; off <<= 1) {   // lex (dist, idx) min
      float pd = __shfl_xor(bd, off);
      int pi = __shfl_xor(bi, off);
      if (pd < bd || (pd == bd && pi < bi)) { bd = pd; bi = pi; }
    }
    if (lane == 0)
      atomicMin(&rowBest[n0 + r],
                ((u64)__float_as_uint(bd) << 32) | (unsigned)bi);
  }
  __syncthreads();

  // ---- epilogue: indices + hist + z_q_st + loss (zt still resident) ----
  if (t < MT) {
    u64 key = atomicMin(&rowBest[n0 + t], 0xFFFFFFFFFFFFFFFFull);  // read
    int bi = (int)(key & 0xFFFFFFFFull);
    kwin[t] = bi;
    atomicAdd(&hist[bi], 1);
    out[(size_t)NELEM + 1 + n0 + t] = (float)bi;
  }
  __syncthreads();

  float lsum = 0.f;
  for (int it = 0; it < MT * DD / 256; ++it) {
    int li = it * 256 + t;
    int d = li >> 5, r = li & 31;
    float ze = zt[r][d];
    float zq = cb[(size_t)kwin[r] * DD + d];
    float diff = __fsub_rn(zq, ze);
    float st = __fadd_rn(ze, diff);        // z_e + (z_q - z_e)
    out[(size_t)(bimg * DD + d) * HW + hw0 + r] = st;
    lsum = fmaf(diff, diff, lsum);
  }
#pragma unroll
  for (int off = 32; off > 0; off >>= 1) lsum += __shfl_down(lsum, off);
  if (lane == 0) lred[w] = lsum;
  __syncthreads();
  if (t == 0)
    atomicAdd(loss_acc, ((lred[0] + lred[1]) + (lred[2] + lred[3])));
}

// ---------------- finalize: vq_loss + perplexity ----------------
__global__ __launch_bounds__(256) void vq_final(const int* __restrict__ hist,
                                                const float* __restrict__ loss,
                                                float* __restrict__ out) {
  __shared__ float sred[256];
  int t = threadIdx.x;
  float s = 0.f;
  for (int k = t; k < KK; k += 256) {
    float p = (float)hist[k] * (1.f / 16384.f);
    s += p * logf(p + 1e-10f);
  }
  sred[t] = s;
  __syncthreads();
  for (int off = 128; off > 0; off >>= 1) {
    if (t < off) sred[t] += sred[t + off];
    __syncthreads();
  }
  if (t == 0) {
    float L = loss[0] / (float)NELEM;
    out[NELEM] = 1.25f * L;
    out[(size_t)NELEM + 1 + NROWS] = expf(-sred[0]);
  }
}

extern "C" void kernel_launch(void* const* d_in, const int* in_sizes, int n_in,
                              void* d_out, int out_size, void* d_ws, size_t ws_size,
                              hipStream_t stream) {
  const float* z = (const float*)d_in[0];   // (16,256,32,32) fp32
  const float* cb = (const float*)d_in[1];  // (8192,256) fp32
  float* out = (float*)d_out;               // fp32: [z_q_st | loss | idx | perp]

  float* wsf = (float*)d_ws;
  int* hist = (int*)d_ws;                          // 8192 ints
  float* loss = wsf + 8192;                        // 1 (+pad)
  float* Bk = wsf + 8448;                          // 8192
  float* Arow = wsf + 16640;                       // 16384
  u64* rowBest = (u64*)(wsf + 33024);              // 16384 u64 (128 KB)
  ushort* cbB = (ushort*)(wsf + 65792);            // 2.10M ushorts (4.2 MB)
  float* cbT = wsf + 65792 + 1048576;              // 2M floats (8 MB)

  hipMemsetAsync(d_ws, 0, 8448 * sizeof(float), stream);
  hipMemsetAsync(rowBest, 0xFF, NROWS * sizeof(u64), stream);
  vq_transpose<<<dim3(KK / 64, DD / 64), 256, 0, stream>>>(cb, cbT);
  vq_norms<<<KK / 256, 256, 0, stream>>>(cb, Bk);
  vq_arow<<<NROWS / 256, 256, 0, stream>>>(z, Arow);
  vq_cbB<<<1024, 256, 0, stream>>>(cb, cbB);
  vq_fused<<<NROWS / MT, 256, 0, stream>>>(z, cbT, cb, cbB, Bk, Arow, out,
                                           hist, loss, rowBest);
  vq_final<<<1, 256, 0, stream>>>(hist, loss, out);
}